// Round 2
// baseline (1839.444 us; speedup 1.0000x reference)
//
#include <hip/hip_runtime.h>
#include <hip/hip_cooperative_groups.h>

namespace cg = cooperative_groups;

// 6-level 2D DB4 wavelet (forward -> soft threshold -> inverse), N=4096 fp32.
// R4: single persistent COOPERATIVE kernel. 1 launch (was 13).
//   - grid-stride over tiles per level, grid.sync() between the 12 phases.
//   - thr_kernel folded into fwd level 5 (writes thr(ll) straight to flat tail).
//   - tile bodies identical to R3 (verified): fwd 32x32-out tiles, inv 64x64-out
//     tiles, register sliding windows, no parity divergence, float4 I/O.
//   - LDS: union of fwd (40320 B) and inv (39168 B) buffers -> 4 blocks/CU.
//
// d_out layout: [0 .. 16777216) reconstruction, [16777216 .. 33554432) flat coeffs.
// Flat per level: row i = [hh_i | hl_i | lh_i], row stride 3*sc; final thr(approx)
// (64x64) at the tail.
// ws layout (floats): approx chain A1..A6 [0 .. 5591040) | P0 (4194304) | P1 (4194304)

__device__ __forceinline__ float thrf(float t, float alpha, float bp, float bm) {
    float s1 = 1.0f / (1.0f + __expf(-alpha * (t - bp)));
    float s2 = 1.0f / (1.0f + __expf( alpha * (t + bm)));
    return t * (s1 + s2);
}

__device__ __forceinline__ void load_filt(const float* __restrict__ filt,
                                          float (&h)[8], float (&w)[8]) {
#pragma unroll
    for (int k = 0; k < 8; ++k) h[k] = filt[k];
#pragma unroll
    for (int k = 0; k < 8; ++k) w[k] = (k & 1) ? -h[7 - k] : h[7 - k];
}

struct SMemF {
    float xs[70][72];   // 20160 B
    float Ds[70][36];   // 10080 B
    float As[70][36];   // 10080 B
};
struct SMemI {
    float hh[36][36], hl[36][36], lh[36][36], as0[36][36]; // 20736 B
    float Hs[64][36], Ls[64][36];                          // 18432 B
};
union SMem {
    SMemF f;  // 40320 B
    SMemI i;  // 39168 B
};

// Forward tile: X (s x s) -> thresholded hh|hl|lh into flat (stride 3*sh)
// + ll into All (stride sh; thresholded too when thr_ll).
__device__ __forceinline__ void fwd_tile(
    SMemF& sm, const float* __restrict__ X, int s, int sh,
    float* __restrict__ flat, float* __restrict__ All, bool thr_ll,
    const float (&hr)[8], const float (&wr)[8],
    const float (&hc)[8], const float (&wc)[8],
    float alpha, float bp, float bm, int i0, int j0, int tid) {
    const int smk = s - 1;
    // stage 1: global -> LDS, float4 chunks (col base shifted to -8 for alignment)
    for (int idx = tid; idx < 70 * 18; idx += 256) {
        int rr = idx / 18, c = idx - rr * 18;
        int gr = (2 * i0 - 7 + rr) & smk;
        int gc = (2 * j0 - 8 + 4 * c) & smk;
        *(float4*)&sm.xs[rr][4 * c] = *(const float4*)&X[(size_t)gr * s + gc];
    }
    __syncthreads();
    // stage 2: row filter, 4 outputs per item from one 16-float window.
    for (int idx = tid; idx < 70 * 8; idx += 256) {
        int rr = idx >> 3, q = idx & 7;
        const float4* xr = (const float4*)&sm.xs[rr][8 * q];
        float wv[16];
#pragma unroll
        for (int m = 0; m < 4; ++m) {
            float4 t = xr[m];
            wv[4 * m + 0] = t.x; wv[4 * m + 1] = t.y;
            wv[4 * m + 2] = t.z; wv[4 * m + 3] = t.w;
        }
        float d[4], a[4];
#pragma unroll
        for (int e = 0; e < 4; ++e) {
            float dd = 0.f, aa = 0.f;
#pragma unroll
            for (int u = 0; u < 8; ++u) {
                float v = wv[2 * e + 1 + u];
                dd += wr[7 - u] * v;
                aa += hr[7 - u] * v;
            }
            d[e] = dd; a[e] = aa;
        }
        *(float4*)&sm.Ds[rr][4 * q] = make_float4(d[0], d[1], d[2], d[3]);
        *(float4*)&sm.As[rr][4 * q] = make_float4(a[0], a[1], a[2], a[3]);
    }
    __syncthreads();
    // stage 3: col filter + threshold + store; 4 outputs from a 14-row window.
    {
        const int j = tid & 31, iq = tid >> 5;
        float Dw[14], Aw[14];
#pragma unroll
        for (int t = 0; t < 14; ++t) {
            Dw[t] = sm.Ds[8 * iq + t][j];
            Aw[t] = sm.As[8 * iq + t][j];
        }
#pragma unroll
        for (int e = 0; e < 4; ++e) {
            float hh = 0.f, hl = 0.f, lh = 0.f, ll = 0.f;
#pragma unroll
            for (int u = 0; u < 8; ++u) {
                float dv = Dw[2 * e + u], av = Aw[2 * e + u];
                hh += wc[7 - u] * dv;
                hl += hc[7 - u] * dv;
                lh += wc[7 - u] * av;
                ll += hc[7 - u] * av;
            }
            int row = i0 + 4 * iq + e;
            size_t ro = (size_t)row * (3 * sh) + (j0 + j);
            flat[ro]          = thrf(hh, alpha, bp, bm);
            flat[ro + sh]     = thrf(hl, alpha, bp, bm);
            flat[ro + 2 * sh] = thrf(lh, alpha, bp, bm);
            All[(size_t)row * sh + (j0 + j)] =
                thr_ll ? thrf(ll, alpha, bp, bm) : ll;
        }
    }
}

// Inverse tile: hh|hl|lh (stride 3*sc) + a (stride astride) -> 64x64 out tile.
__device__ __forceinline__ void inv_tile(
    SMemI& sm, const float* __restrict__ flatl, const float* __restrict__ a,
    int astride, int sc, float* __restrict__ outp, int ostride,
    const float (&hr)[8], const float (&wr)[8],
    const float (&hc)[8], const float (&wc)[8],
    int i0, int m0, int tid) {
    const int mm = sc - 1;
    const int r0 = i0 >> 1, c0 = m0 >> 1;
    const int ds = 3 * sc;
    // stage 1: load 36x36 tiles of all four coefficient arrays as float4 chunks.
    for (int idx = tid; idx < 4 * 324; idx += 256) {
        int aid = idx / 324, rem = idx - aid * 324;
        int rr = rem / 9, c = rem - rr * 9;
        int gr = (r0 + rr) & mm;
        int gc = (c0 + 4 * c) & mm;
        if (aid == 0)
            *(float4*)&sm.hh[rr][4 * c] = *(const float4*)&flatl[(size_t)gr * ds + gc];
        else if (aid == 1)
            *(float4*)&sm.hl[rr][4 * c] = *(const float4*)&flatl[(size_t)gr * ds + sc + gc];
        else if (aid == 2)
            *(float4*)&sm.lh[rr][4 * c] = *(const float4*)&flatl[(size_t)gr * ds + 2 * sc + gc];
        else
            *(float4*)&sm.as0[rr][4 * c] = *(const float4*)&a[(size_t)gr * astride + gc];
    }
    __syncthreads();
    // stage 2: col inverse, 4 rows per item from a 6-row window (no divergence).
    for (int idx = tid; idx < 16 * 36; idx += 256) {
        int q = idx / 36, jj = idx - q * 36;
        float hv[6], lv[6], gv[6], av[6];
#pragma unroll
        for (int d = 0; d < 6; ++d) {
            int lr = 2 * q + d;
            hv[d] = sm.hh[lr][jj];
            lv[d] = sm.hl[lr][jj];
            gv[d] = sm.lh[lr][jj];
            av[d] = sm.as0[lr][jj];
        }
        float H0 = 0.f, H1 = 0.f, H2 = 0.f, H3 = 0.f;
        float L0 = 0.f, L1 = 0.f, L2 = 0.f, L3 = 0.f;
#pragma unroll
        for (int t = 0; t < 4; ++t) {
            float we = wc[2 * t], he = hc[2 * t];
            float wo = wc[2 * t + 1], ho = hc[2 * t + 1];
            H0 += we * hv[t]     + he * lv[t];
            H1 += wo * hv[t + 1] + ho * lv[t + 1];
            H2 += we * hv[t + 1] + he * lv[t + 1];
            H3 += wo * hv[t + 2] + ho * lv[t + 2];
            L0 += we * gv[t]     + he * av[t];
            L1 += wo * gv[t + 1] + ho * av[t + 1];
            L2 += we * gv[t + 1] + he * av[t + 1];
            L3 += wo * gv[t + 2] + ho * av[t + 2];
        }
        sm.Hs[4 * q + 0][jj] = H0; sm.Hs[4 * q + 1][jj] = H1;
        sm.Hs[4 * q + 2][jj] = H2; sm.Hs[4 * q + 3][jj] = H3;
        sm.Ls[4 * q + 0][jj] = L0; sm.Ls[4 * q + 1][jj] = L1;
        sm.Ls[4 * q + 2][jj] = L2; sm.Ls[4 * q + 3][jj] = L3;
    }
    __syncthreads();
    // stage 3: row inverse, 4 outputs per item from a 6-col window, float4 store.
    for (int idx = tid; idx < 64 * 16; idx += 256) {
        int i = idx >> 4, p = idx & 15;
        const float2* hp = (const float2*)&sm.Hs[i][2 * p];
        const float2* lp = (const float2*)&sm.Ls[i][2 * p];
        float2 hA = hp[0], hB = hp[1], hC = hp[2];
        float2 lA = lp[0], lB = lp[1], lC = lp[2];
        float Hw[6] = {hA.x, hA.y, hB.x, hB.y, hC.x, hC.y};
        float Lw[6] = {lA.x, lA.y, lB.x, lB.y, lC.x, lC.y};
        float o0 = 0.f, o1 = 0.f, o2 = 0.f, o3 = 0.f;
#pragma unroll
        for (int t = 0; t < 4; ++t) {
            float we = wr[2 * t], he = hr[2 * t];
            float wo = wr[2 * t + 1], ho = hr[2 * t + 1];
            o0 += we * Hw[t]     + he * Lw[t];
            o1 += wo * Hw[t + 1] + ho * Lw[t + 1];
            o2 += we * Hw[t + 1] + he * Lw[t + 1];
            o3 += wo * Hw[t + 2] + ho * Lw[t + 2];
        }
        *(float4*)&outp[(size_t)(i0 + i) * ostride + (m0 + 4 * p)] =
            make_float4(o0, o1, o2, o3);
    }
}

__global__ __launch_bounds__(256, 4) void mega(
    const float* __restrict__ x, const float* __restrict__ scal,
    const float* __restrict__ ap, const float* __restrict__ bpp,
    const float* __restrict__ bmp, float* __restrict__ out,
    float* __restrict__ ws) {
    cg::grid_group grid = cg::this_grid();
    __shared__ SMem smem;
    const int tid = threadIdx.x;
    const int bid = blockIdx.x;
    const int nb  = gridDim.x;
    const float alpha = *ap, bp = *bpp, bm = *bmp;

    const int N = 4096;
    float* recon = out;
    float* flat  = out + 16777216;
    const size_t Aoff[7]    = {0, 0, 4194304, 5242880, 5505024, 5570560, 5586944};
    const size_t flatOff[6] = {0, 12582912, 15728640, 16515072, 16711680, 16760832};
    const size_t finalOff = 16773120;
    float* P0 = ws + 5591040;
    float* P1 = ws + 5591040 + 4194304;

    // ---------------- Forward (6 phases) ----------------
    const float* src = x;
    for (int lev = 0; lev < 6; ++lev) {
        int s = N >> lev, sh = s >> 1;
        float hr[8], wr[8], hc[8], wc[8];
        load_filt(scal + lev * 8, hr, wr);
        load_filt(scal + (lev + 1) * 8, hc, wc);
        float* All = (lev < 5) ? (ws + Aoff[lev + 1]) : (flat + finalOff);
        bool thr_ll = (lev == 5);
        int nt = sh >> 5;
        for (int t = bid; t < nt * nt; t += nb) {
            int ty = t / nt, tx = t - ty * nt;
            fwd_tile(smem.f, src, s, sh, flat + flatOff[lev], All, thr_ll,
                     hr, wr, hc, wc, alpha, bp, bm, ty * 32, tx * 32, tid);
        }
        src = ws + Aoff[lev + 1];
        __threadfence();
        grid.sync();
    }

    // ---------------- Inverse (6 phases) ----------------
    const float* a_in = flat + finalOff;
    for (int lev = 5; lev >= 0; --lev) {
        int sc = N >> (lev + 1), r = 2 * sc;
        float hr[8], wr[8], hc[8], wc[8];
        load_filt(scal + lev * 8, hr, wr);        // row filter
        load_filt(scal + (lev + 1) * 8, hc, wc);  // col filter
        float* outp = (lev == 0) ? recon : ((lev & 1) ? P1 : P0);
        int nt = r >> 6;
        for (int t = bid; t < nt * nt; t += nb) {
            int ty = t / nt, tx = t - ty * nt;
            inv_tile(smem.i, flat + flatOff[lev], a_in, sc, sc, outp, r,
                     hr, wr, hc, wc, ty * 64, tx * 64, tid);
        }
        a_in = outp;
        if (lev) { __threadfence(); grid.sync(); }
    }
}

extern "C" void kernel_launch(void* const* d_in, const int* in_sizes, int n_in,
                              void* d_out, int out_size, void* d_ws, size_t ws_size,
                              hipStream_t stream) {
    const float* x    = (const float*)d_in[0];
    const float* scal = (const float*)d_in[1];  // 12 x 8
    const float* ap   = (const float*)d_in[2];
    const float* bp   = (const float*)d_in[3];
    const float* bm   = (const float*)d_in[4];
    float* out = (float*)d_out;
    float* ws  = (float*)d_ws;

    // Co-resident grid size: occupancy/CU x 256 CUs (pure host query, graph-safe).
    static int nblk = 0;
    if (nblk == 0) {
        int maxb = 0;
        hipOccupancyMaxActiveBlocksPerMultiprocessor(&maxb, mega, 256, 0);
        if (maxb < 1) maxb = 1;
        nblk = maxb * 256;
        if (nblk > 4096) nblk = 4096;
    }

    void* args[] = {(void*)&x, (void*)&scal, (void*)&ap, (void*)&bp,
                    (void*)&bm, (void*)&out, (void*)&ws};
    hipLaunchCooperativeKernel(mega, dim3(nblk), dim3(256), args, 0, stream);
}

// Round 3
// 349.364 us; speedup vs baseline: 5.2651x; 5.2651x over previous
//
#include <hip/hip_runtime.h>

// 6-level 2D DB4 wavelet (forward -> soft threshold -> inverse), N=4096 fp32.
// R5: hybrid launch structure. 7 launches (was 13 in R3; R4's single coop kernel
// with cg::grid.sync() at 1024 WGs cost ~165us/sync -> 1839us, reverted).
//   - levels 0..2 fwd/inv: separate launches (memory-bound, R3-verified bodies).
//   - levels 3..5 fwd + thr + inv 5..3: ONE cooperative kernel, 64 WGs, custom
//     lightweight global barrier (atomicAdd counter + generation flag, agent-scope
//     acquire/release, s_sleep spin). 5 barriers total, each among only 64 WGs.
//   - barrier state in ws tail, reset by fwd lev2 kernel (strictly precedes core).
//
// d_out layout: [0 .. 16777216) reconstruction, [16777216 .. 33554432) flat coeffs.
// Flat per level: row i = [hh_i | hl_i | lh_i], row stride 3*sc; final thr(approx)
// (64x64) at the tail.
// ws layout (floats): A1..A6 [0 .. 5591040) | P0 (4194304) | P1 (4194304) |
// barrier pair at float offset 14680064.

#define CORE_WGS 64

__device__ __forceinline__ float thrf(float t, float alpha, float bp, float bm) {
    float s1 = 1.0f / (1.0f + __expf(-alpha * (t - bp)));
    float s2 = 1.0f / (1.0f + __expf( alpha * (t + bm)));
    return t * (s1 + s2);
}

__device__ __forceinline__ void load_filt(const float* __restrict__ filt,
                                          float (&h)[8], float (&w)[8]) {
#pragma unroll
    for (int k = 0; k < 8; ++k) h[k] = filt[k];
#pragma unroll
    for (int k = 0; k < 8; ++k) w[k] = (k & 1) ? -h[7 - k] : h[7 - k];
}

struct SMemF {
    float xs[70][72];   // 20160 B
    float Ds[70][36];   // 10080 B
    float As[70][36];   // 10080 B
};
struct SMemI {
    float hh[36][36], hl[36][36], lh[36][36], as0[36][36]; // 20736 B
    float Hs[64][36], Ls[64][36];                          // 18432 B
};
union SMem {
    SMemF f;  // 40320 B
    SMemI i;  // 39168 B
};

// ---- lightweight 64-WG global barrier (bar[0]=arrival count, bar[1]=generation)
__device__ __forceinline__ void gbar(unsigned* bar, unsigned k, unsigned nwg, int tid) {
    __syncthreads();
    if (tid == 0) {
        __threadfence();  // release: flush this WG's writes (L2 wb) before arrival
        unsigned old = atomicAdd(&bar[0], 1u);
        if (old == k * nwg - 1u) {
            __hip_atomic_store(&bar[1], k, __ATOMIC_RELEASE, __HIP_MEMORY_SCOPE_AGENT);
            // acquire to invalidate any stale cached lines before next phase
            (void)__hip_atomic_load(&bar[1], __ATOMIC_ACQUIRE, __HIP_MEMORY_SCOPE_AGENT);
        } else {
            unsigned g;
            do {
                __builtin_amdgcn_s_sleep(2);
                g = __hip_atomic_load(&bar[1], __ATOMIC_ACQUIRE, __HIP_MEMORY_SCOPE_AGENT);
            } while (g < k);
        }
    }
    __syncthreads();
}

// Forward tile: X (s x s) -> thresholded hh|hl|lh into flat (stride 3*sh)
// + ll into All (stride sh; thresholded too when thr_ll).
__device__ __forceinline__ void fwd_tile(
    SMemF& sm, const float* __restrict__ X, int s, int sh,
    float* __restrict__ flat, float* __restrict__ All, bool thr_ll,
    const float (&hr)[8], const float (&wr)[8],
    const float (&hc)[8], const float (&wc)[8],
    float alpha, float bp, float bm, int i0, int j0, int tid) {
    const int smk = s - 1;
    // stage 1: global -> LDS, float4 chunks (col base shifted to -8 for alignment)
    for (int idx = tid; idx < 70 * 18; idx += 256) {
        int rr = idx / 18, c = idx - rr * 18;
        int gr = (2 * i0 - 7 + rr) & smk;
        int gc = (2 * j0 - 8 + 4 * c) & smk;
        *(float4*)&sm.xs[rr][4 * c] = *(const float4*)&X[(size_t)gr * s + gc];
    }
    __syncthreads();
    // stage 2: row filter, 4 outputs per item from one 16-float window.
    for (int idx = tid; idx < 70 * 8; idx += 256) {
        int rr = idx >> 3, q = idx & 7;
        const float4* xr = (const float4*)&sm.xs[rr][8 * q];
        float wv[16];
#pragma unroll
        for (int m = 0; m < 4; ++m) {
            float4 t = xr[m];
            wv[4 * m + 0] = t.x; wv[4 * m + 1] = t.y;
            wv[4 * m + 2] = t.z; wv[4 * m + 3] = t.w;
        }
        float d[4], a[4];
#pragma unroll
        for (int e = 0; e < 4; ++e) {
            float dd = 0.f, aa = 0.f;
#pragma unroll
            for (int u = 0; u < 8; ++u) {
                float v = wv[2 * e + 1 + u];
                dd += wr[7 - u] * v;
                aa += hr[7 - u] * v;
            }
            d[e] = dd; a[e] = aa;
        }
        *(float4*)&sm.Ds[rr][4 * q] = make_float4(d[0], d[1], d[2], d[3]);
        *(float4*)&sm.As[rr][4 * q] = make_float4(a[0], a[1], a[2], a[3]);
    }
    __syncthreads();
    // stage 3: col filter + threshold + store; 4 outputs from a 14-row window.
    {
        const int j = tid & 31, iq = tid >> 5;
        float Dw[14], Aw[14];
#pragma unroll
        for (int t = 0; t < 14; ++t) {
            Dw[t] = sm.Ds[8 * iq + t][j];
            Aw[t] = sm.As[8 * iq + t][j];
        }
#pragma unroll
        for (int e = 0; e < 4; ++e) {
            float hh = 0.f, hl = 0.f, lh = 0.f, ll = 0.f;
#pragma unroll
            for (int u = 0; u < 8; ++u) {
                float dv = Dw[2 * e + u], av = Aw[2 * e + u];
                hh += wc[7 - u] * dv;
                hl += hc[7 - u] * dv;
                lh += wc[7 - u] * av;
                ll += hc[7 - u] * av;
            }
            int row = i0 + 4 * iq + e;
            size_t ro = (size_t)row * (3 * sh) + (j0 + j);
            flat[ro]          = thrf(hh, alpha, bp, bm);
            flat[ro + sh]     = thrf(hl, alpha, bp, bm);
            flat[ro + 2 * sh] = thrf(lh, alpha, bp, bm);
            All[(size_t)row * sh + (j0 + j)] =
                thr_ll ? thrf(ll, alpha, bp, bm) : ll;
        }
    }
}

// Inverse tile: hh|hl|lh (stride 3*sc) + a (stride astride) -> 64x64 out tile.
__device__ __forceinline__ void inv_tile(
    SMemI& sm, const float* __restrict__ flatl, const float* __restrict__ a,
    int astride, int sc, float* __restrict__ outp, int ostride,
    const float (&hr)[8], const float (&wr)[8],
    const float (&hc)[8], const float (&wc)[8],
    int i0, int m0, int tid) {
    const int mm = sc - 1;
    const int r0 = i0 >> 1, c0 = m0 >> 1;
    const int ds = 3 * sc;
    // stage 1: load 36x36 tiles of all four coefficient arrays as float4 chunks.
    for (int idx = tid; idx < 4 * 324; idx += 256) {
        int aid = idx / 324, rem = idx - aid * 324;
        int rr = rem / 9, c = rem - rr * 9;
        int gr = (r0 + rr) & mm;
        int gc = (c0 + 4 * c) & mm;
        if (aid == 0)
            *(float4*)&sm.hh[rr][4 * c] = *(const float4*)&flatl[(size_t)gr * ds + gc];
        else if (aid == 1)
            *(float4*)&sm.hl[rr][4 * c] = *(const float4*)&flatl[(size_t)gr * ds + sc + gc];
        else if (aid == 2)
            *(float4*)&sm.lh[rr][4 * c] = *(const float4*)&flatl[(size_t)gr * ds + 2 * sc + gc];
        else
            *(float4*)&sm.as0[rr][4 * c] = *(const float4*)&a[(size_t)gr * astride + gc];
    }
    __syncthreads();
    // stage 2: col inverse, 4 rows per item from a 6-row window (no divergence).
    for (int idx = tid; idx < 16 * 36; idx += 256) {
        int q = idx / 36, jj = idx - q * 36;
        float hv[6], lv[6], gv[6], av[6];
#pragma unroll
        for (int d = 0; d < 6; ++d) {
            int lr = 2 * q + d;
            hv[d] = sm.hh[lr][jj];
            lv[d] = sm.hl[lr][jj];
            gv[d] = sm.lh[lr][jj];
            av[d] = sm.as0[lr][jj];
        }
        float H0 = 0.f, H1 = 0.f, H2 = 0.f, H3 = 0.f;
        float L0 = 0.f, L1 = 0.f, L2 = 0.f, L3 = 0.f;
#pragma unroll
        for (int t = 0; t < 4; ++t) {
            float we = wc[2 * t], he = hc[2 * t];
            float wo = wc[2 * t + 1], ho = hc[2 * t + 1];
            H0 += we * hv[t]     + he * lv[t];
            H1 += wo * hv[t + 1] + ho * lv[t + 1];
            H2 += we * hv[t + 1] + he * lv[t + 1];
            H3 += wo * hv[t + 2] + ho * lv[t + 2];
            L0 += we * gv[t]     + he * av[t];
            L1 += wo * gv[t + 1] + ho * av[t + 1];
            L2 += we * gv[t + 1] + he * av[t + 1];
            L3 += wo * gv[t + 2] + ho * av[t + 2];
        }
        sm.Hs[4 * q + 0][jj] = H0; sm.Hs[4 * q + 1][jj] = H1;
        sm.Hs[4 * q + 2][jj] = H2; sm.Hs[4 * q + 3][jj] = H3;
        sm.Ls[4 * q + 0][jj] = L0; sm.Ls[4 * q + 1][jj] = L1;
        sm.Ls[4 * q + 2][jj] = L2; sm.Ls[4 * q + 3][jj] = L3;
    }
    __syncthreads();
    // stage 3: row inverse, 4 outputs per item from a 6-col window, float4 store.
    for (int idx = tid; idx < 64 * 16; idx += 256) {
        int i = idx >> 4, p = idx & 15;
        const float2* hp = (const float2*)&sm.Hs[i][2 * p];
        const float2* lp = (const float2*)&sm.Ls[i][2 * p];
        float2 hA = hp[0], hB = hp[1], hC = hp[2];
        float2 lA = lp[0], lB = lp[1], lC = lp[2];
        float Hw[6] = {hA.x, hA.y, hB.x, hB.y, hC.x, hC.y};
        float Lw[6] = {lA.x, lA.y, lB.x, lB.y, lC.x, lC.y};
        float o0 = 0.f, o1 = 0.f, o2 = 0.f, o3 = 0.f;
#pragma unroll
        for (int t = 0; t < 4; ++t) {
            float we = wr[2 * t], he = hr[2 * t];
            float wo = wr[2 * t + 1], ho = hr[2 * t + 1];
            o0 += we * Hw[t]     + he * Lw[t];
            o1 += wo * Hw[t + 1] + ho * Lw[t + 1];
            o2 += we * Hw[t + 1] + he * Lw[t + 1];
            o3 += wo * Hw[t + 2] + ho * Lw[t + 2];
        }
        *(float4*)&outp[(size_t)(i0 + i) * ostride + (m0 + 4 * p)] =
            make_float4(o0, o1, o2, o3);
    }
}

// ---- standalone kernels for big levels (0..2), one tile per block ----
__global__ __launch_bounds__(256) void fwd_fused(
    const float* __restrict__ X, int s, int sh,
    float* __restrict__ flat, float* __restrict__ All,
    const float* __restrict__ filt_row, const float* __restrict__ filt_col,
    const float* __restrict__ ap, const float* __restrict__ bpp,
    const float* __restrict__ bmp, unsigned* bar_reset) {
    __shared__ SMem smem;
    float hr[8], wr[8], hc[8], wc[8];
    load_filt(filt_row, hr, wr);
    load_filt(filt_col, hc, wc);
    const float alpha = *ap, bp = *bpp, bm = *bmp;
    fwd_tile(smem.f, X, s, sh, flat, All, false, hr, wr, hc, wc,
             alpha, bp, bm, blockIdx.y * 32, blockIdx.x * 32, threadIdx.x);
    if (bar_reset && blockIdx.x == 0 && blockIdx.y == 0 && threadIdx.x == 0) {
        bar_reset[0] = 0u;
        bar_reset[1] = 0u;
    }
}

__global__ __launch_bounds__(256) void inv_fused(
    const float* __restrict__ flatl, const float* __restrict__ a, int astride,
    int sc, float* __restrict__ outp, int ostride,
    const float* __restrict__ filt_col, const float* __restrict__ filt_row) {
    __shared__ SMem smem;
    float hr[8], wr[8], hc[8], wc[8];
    load_filt(filt_row, hr, wr);
    load_filt(filt_col, hc, wc);
    inv_tile(smem.i, flatl, a, astride, sc, outp, ostride, hr, wr, hc, wc,
             blockIdx.y * 64, blockIdx.x * 64, threadIdx.x);
}

// ---- fused small-level core: fwd 3..5 (+thr) and inv 5..3, 64 WGs ----
__global__ __launch_bounds__(256) void core_small(
    const float* __restrict__ scal, const float* __restrict__ ap,
    const float* __restrict__ bpp, const float* __restrict__ bmp,
    float* __restrict__ out, float* __restrict__ ws, unsigned* bar) {
    __shared__ SMem smem;
    const int tid = threadIdx.x, bid = blockIdx.x, nb = gridDim.x;
    const float alpha = *ap, bp = *bpp, bm = *bmp;
    const int N = 4096;
    float* flat = out + 16777216;
    const size_t Aoff[7]    = {0, 0, 4194304, 5242880, 5505024, 5570560, 5586944};
    const size_t flatOff[6] = {0, 12582912, 15728640, 16515072, 16711680, 16760832};
    const size_t finalOff = 16773120;
    float* P0 = ws + 5591040;
    float* P1 = ws + 5591040 + 4194304;

    unsigned k = 1;
    // forward levels 3..5 (thr of final approx folded into lev 5)
    for (int lev = 3; lev <= 5; ++lev) {
        int s = N >> lev, sh = s >> 1;
        float hr[8], wr[8], hc[8], wc[8];
        load_filt(scal + lev * 8, hr, wr);
        load_filt(scal + (lev + 1) * 8, hc, wc);
        const float* src = ws + Aoff[lev];
        float* All = (lev < 5) ? (ws + Aoff[lev + 1]) : (flat + finalOff);
        int nt = sh >> 5;
        for (int t = bid; t < nt * nt; t += nb)
            fwd_tile(smem.f, src, s, sh, flat + flatOff[lev], All, lev == 5,
                     hr, wr, hc, wc, alpha, bp, bm, (t / nt) * 32, (t % nt) * 32, tid);
        gbar(bar, k++, (unsigned)nb, tid);
    }
    // inverse levels 5..3
    const float* a_in = flat + finalOff;
    for (int lev = 5; lev >= 3; --lev) {
        int sc = N >> (lev + 1), r = 2 * sc;
        float hr[8], wr[8], hc[8], wc[8];
        load_filt(scal + lev * 8, hr, wr);
        load_filt(scal + (lev + 1) * 8, hc, wc);
        float* outp = (lev & 1) ? P1 : P0;
        int nt = r >> 6;
        for (int t = bid; t < nt * nt; t += nb)
            inv_tile(smem.i, flat + flatOff[lev], a_in, sc, sc, outp, r,
                     hr, wr, hc, wc, (t / nt) * 64, (t % nt) * 64, tid);
        a_in = outp;
        if (lev > 3) gbar(bar, k++, (unsigned)nb, tid);
    }
}

extern "C" void kernel_launch(void* const* d_in, const int* in_sizes, int n_in,
                              void* d_out, int out_size, void* d_ws, size_t ws_size,
                              hipStream_t stream) {
    const float* x    = (const float*)d_in[0];
    const float* scal = (const float*)d_in[1];  // 12 x 8
    const float* ap   = (const float*)d_in[2];
    const float* bp   = (const float*)d_in[3];
    const float* bm   = (const float*)d_in[4];
    float* out = (float*)d_out;
    float* ws  = (float*)d_ws;

    const int N = 4096;
    float* recon = out;
    float* flat  = out + 16777216;
    static const size_t Aoff[7]    = {0, 0, 4194304, 5242880, 5505024, 5570560, 5586944};
    static const size_t flatOff[6] = {0, 12582912, 15728640, 16515072, 16711680, 16760832};
    float* P0 = ws + 5591040;
    float* P1 = ws + 5591040 + 4194304;
    unsigned* bar = (unsigned*)(ws + 14680064);  // 56 MB offset, past all live data

    dim3 blk(256);

    // ---------------- Forward big levels 0..2 ----------------
    const float* src = x;
    for (int lev = 0; lev < 3; ++lev) {
        int s = N >> lev, sh = s >> 1;
        dim3 g(sh / 32, sh / 32);
        fwd_fused<<<g, blk, 0, stream>>>(src, s, sh, flat + flatOff[lev],
                                         ws + Aoff[lev + 1],
                                         scal + lev * 8, scal + (lev + 1) * 8,
                                         ap, bp, bm,
                                         (lev == 2) ? bar : (unsigned*)nullptr);
        src = ws + Aoff[lev + 1];
    }

    // ---------------- Fused small levels (fwd 3..5, thr, inv 5..3) ----------------
    {
        void* args[] = {(void*)&scal, (void*)&ap, (void*)&bp, (void*)&bm,
                        (void*)&out, (void*)&ws, (void*)&bar};
        hipLaunchCooperativeKernel(core_small, dim3(CORE_WGS), blk, args, 0, stream);
    }

    // ---------------- Inverse big levels 2..0 ----------------
    const float* a_in = P1;  // inv lev3 (in core) wrote P1
    for (int lev = 2; lev >= 0; --lev) {
        int sc = N >> (lev + 1), r = 2 * sc;
        float* outp = (lev == 0) ? recon : ((lev & 1) ? P1 : P0);
        dim3 g(r / 64, r / 64);
        inv_fused<<<g, blk, 0, stream>>>(flat + flatOff[lev], a_in, sc,
                                         sc, outp, r,
                                         scal + (lev + 1) * 8, scal + lev * 8);
        a_in = outp;
    }
}